// Round 10
// baseline (183.533 us; speedup 1.0000x reference)
//
#include <hip/hip_runtime.h>
#include <hip/hip_cooperative_groups.h>
#include <stdint.h>

namespace cg = cooperative_groups;

// FMFMNeuron LIF scan — single cooperative kernel, 3 phases:
//  P1 compress: 134MB f32 spikes -> 4MB 2-bit cur-codes [T/16][B] (nt loads)
//  P2 scanA: C=16 chunks x B neurons; 768-step warmup from mem=0 (chunks 0..2
//     clamped => exact), 256-step body writes f32 spikes to out (nt stores),
//     (start,end) state to spec[].
//  P3 scanB: chain chunks by bit-comparing true state vs spec start; match ->
//     adopt spec end; mismatch -> recompute chunk exactly + patch out.
//     Bit-exact REGARDLESS of speculation quality.
// grid.sync() between phases (256 blocks = 1/CU, co-resident);
// __threadfence() for cross-XCD visibility of codes/spec.
//
// Step math (absmax=0, rounds 1..9): spikes in {0,1} =>
//   cur in {0, w1, w2, fadd(w1,w2)} exactly; strict left-to-right:
//   m = fsub(fadd(fmul(0.95f,mem), cur), rst); spk = m>1.0f; rst' = spk.

#define T_STEPS 4096
#define B_NEUR  4096
#define NCHUNK  16
#define CH_W    16                     // code words per chunk body
#define WARM_W  48                     // warmup words (768 steps)
#define KG      (T_STEPS / 16)         // 256 code words per neuron

typedef float f4v __attribute__((ext_vector_type(4)));

// ---- phase helpers ---------------------------------------------------------
__device__ __forceinline__ void compress_item(
    const f4v* __restrict__ sp4, uint32_t* __restrict__ codes, int tid)
{
    const int b2 = tid & (B_NEUR / 2 - 1);
    const int kg = tid >> 11;
    const f4v* p = sp4 + (size_t)kg * 16 * (B_NEUR / 2) + b2;
    uint32_t we = 0, wo = 0;
    #pragma unroll
    for (int i = 0; i < 16; ++i) {
        f4v s = __builtin_nontemporal_load(p + (size_t)i * (B_NEUR / 2));
        uint32_t ce = (s.x != 0.0f ? 1u : 0u) | (s.y != 0.0f ? 2u : 0u);
        uint32_t co = (s.z != 0.0f ? 1u : 0u) | (s.w != 0.0f ? 2u : 0u);
        we |= ce << (2 * i);
        wo |= co << (2 * i);
    }
    *reinterpret_cast<uint2*>(codes + (size_t)kg * B_NEUR + 2 * b2) =
        make_uint2(we, wo);
}

__device__ __forceinline__ void scanA_item(
    const uint32_t* __restrict__ codes, float* __restrict__ out,
    uint4* __restrict__ spec, const float2* lut2, int tid)
{
    const int b = tid & (B_NEUR - 1);
    const int c = tid >> 12;                        // chunk 0..15
    const int body_w0 = c * CH_W;
    const int w_start = (body_w0 >= WARM_W) ? body_w0 - WARM_W : 0;
    const int w_end   = body_w0 + CH_W;
    const uint32_t* cp = codes + b;

#define CLD(IDX) cp[(size_t)((IDX) < w_end ? (IDX) : (w_end - 1)) * B_NEUR]
#define DECODE2(WORD, D)                                                  \
    {                                                                     \
        _Pragma("unroll")                                                 \
        for (int _j = 0; _j < 8; ++_j)                                    \
            D[_j] = lut2[((WORD) >> (4 * _j)) & 0xFu];                    \
    }
#define STEPN(CUR)                                                        \
    {                                                                     \
        float _m = __fsub_rn(__fadd_rn(__fmul_rn(0.95f, mem), (CUR)),     \
                             rst);                                        \
        rst = (_m > 1.0f) ? 1.0f : 0.0f;                                  \
        mem = _m;                                                         \
    }
#define STEPS_(CUR, Q, K)                                                 \
    {                                                                     \
        float _m = __fsub_rn(__fadd_rn(__fmul_rn(0.95f, mem), (CUR)),     \
                             rst);                                        \
        rst = (_m > 1.0f) ? 1.0f : 0.0f;                                  \
        mem = _m;                                                         \
        __builtin_nontemporal_store(rst, (Q) + (size_t)(K) * B_NEUR);     \
    }
#define CHAIN16N(D)                                                       \
    {                                                                     \
        _Pragma("unroll")                                                 \
        for (int _j = 0; _j < 8; ++_j) { STEPN(D[_j].x) STEPN(D[_j].y) }  \
    }
#define CHAIN16S(D, WIDX)                                                 \
    {                                                                     \
        float* _q = out + (size_t)(WIDX) * 16 * B_NEUR + b;               \
        _Pragma("unroll")                                                 \
        for (int _j = 0; _j < 8; ++_j) {                                  \
            STEPS_(D[_j].x, _q, 2 * _j)                                   \
            STEPS_(D[_j].y, _q, 2 * _j + 1)                               \
        }                                                                 \
    }

    uint32_t pa = CLD(w_start);
    uint32_t pb = CLD(w_start + 1);
    uint32_t pc = CLD(w_start + 2);
    uint32_t pd = CLD(w_start + 3);

    float2 dA[8], dB[8];
    DECODE2(pa, dA)

    float mem = 0.0f, rst = 0.0f;

    for (int iw = w_start; iw < body_w0; iw += 2) {   // warmup, no stores
        uint32_t t0 = CLD(iw + 4);
        DECODE2(pb, dB)
        CHAIN16N(dA)
        pa = pb; pb = pc; pc = pd; pd = t0;
        uint32_t t1 = CLD(iw + 5);
        DECODE2(pb, dA)
        CHAIN16N(dB)
        pa = pb; pb = pc; pc = pd; pd = t1;
    }

    const float sm = mem;
    const float sr = rst;

    for (int iw = body_w0; iw < w_end; iw += 2) {     // body, nt stores
        uint32_t t0 = CLD(iw + 4);
        DECODE2(pb, dB)
        CHAIN16S(dA, iw)
        pa = pb; pb = pc; pc = pd; pd = t0;
        uint32_t t1 = CLD(iw + 5);
        DECODE2(pb, dA)
        CHAIN16S(dB, iw + 1)
        pa = pb; pb = pc; pc = pd; pd = t1;
    }

    uint4 sv;
    sv.x = __float_as_uint(sm);
    sv.y = (sr != 0.0f) ? 1u : 0u;
    sv.z = __float_as_uint(mem);
    sv.w = (rst != 0.0f) ? 1u : 0u;
    spec[(size_t)c * B_NEUR + b] = sv;

#undef CLD
#undef DECODE2
#undef STEPN
#undef STEPS_
#undef CHAIN16N
#undef CHAIN16S
}

__device__ __forceinline__ void scanB_item(
    const uint32_t* __restrict__ codes, float w1, float w2, float w12,
    float* __restrict__ out, const uint4* __restrict__ spec, int b)
{
    float mem = 0.0f, rst = 0.0f;
    uint4 sn = spec[b];
    for (int c = 0; c < NCHUNK; ++c) {
        uint4 s = sn;
        if (c + 1 < NCHUNK) sn = spec[(size_t)(c + 1) * B_NEUR + b];
        bool ok = (s.x == __float_as_uint(mem)) &&
                  ((s.y != 0u) == (rst != 0.0f));
        if (ok) {
            mem = __uint_as_float(s.z);
            rst = s.w ? 1.0f : 0.0f;
        } else {
            for (int wi = 0; wi < CH_W; ++wi) {
                uint32_t w = codes[(size_t)(c * CH_W + wi) * B_NEUR + b];
                float* q = out + (size_t)(c * CH_W + wi) * 16 * B_NEUR + b;
                #pragma unroll
                for (int j = 0; j < 16; ++j) {
                    uint32_t cc = (w >> (2 * j)) & 3u;
                    float cur = (cc & 1u) ? ((cc & 2u) ? w12 : w1)
                                          : ((cc & 2u) ? w2 : 0.0f);
                    float m = __fsub_rn(__fadd_rn(__fmul_rn(0.95f, mem), cur),
                                        rst);
                    rst = (m > 1.0f) ? 1.0f : 0.0f;
                    mem = m;
                    q[(size_t)j * B_NEUR] = rst;
                }
            }
        }
    }
}

__device__ __forceinline__ void lut_init(float2* lut2, float w1, float w2,
                                         float w12)
{
    if (threadIdx.x < 16) {
        uint32_t e = threadIdx.x;
        uint32_t c0 = e & 3u, c1 = (e >> 2) & 3u;
        float2 v;
        v.x = (c0 & 1u) ? ((c0 & 2u) ? w12 : w1) : ((c0 & 2u) ? w2 : 0.0f);
        v.y = (c1 & 1u) ? ((c1 & 2u) ? w12 : w1) : ((c1 & 2u) ? w2 : 0.0f);
        lut2[e] = v;
    }
}

// ---- single cooperative mega-kernel ----------------------------------------
__global__ __launch_bounds__(256) void fmfm_mega(
    const f4v*   __restrict__ sp4,
    const float* __restrict__ W,
    float*       __restrict__ out,
    uint32_t*    __restrict__ codes,
    uint4*       __restrict__ spec)
{
    __shared__ float2 lut2[16];
    const float w1  = W[0];
    const float w2  = W[1];
    const float w12 = __fadd_rn(w1, w2);
    lut_init(lut2, w1, w2, w12);
    __syncthreads();

    const int tid0 = blockIdx.x * 256 + threadIdx.x;   // 0..65535

    // P1: compress — 512K items, 8 per thread
    #pragma unroll
    for (int it = 0; it < 8; ++it)
        compress_item(sp4, codes, tid0 + it * 65536);

    __threadfence();
    cg::this_grid().sync();

    // P2: speculative chunk scan with direct f32 output
    scanA_item(codes, out, spec, lut2, tid0);

    __threadfence();
    cg::this_grid().sync();

    // P3: exact chaining / patch
    if (tid0 < B_NEUR)
        scanB_item(codes, w1, w2, w12, out, spec, tid0);
}

// ---- standalone kernels (fallback path) ------------------------------------
__global__ __launch_bounds__(256) void fmfm_compress(
    const f4v* __restrict__ sp4, uint32_t* __restrict__ codes)
{
    compress_item(sp4, codes, blockIdx.x * 256 + threadIdx.x);
}

__global__ __launch_bounds__(256) void fmfm_scanA(
    const uint32_t* __restrict__ codes, const float* __restrict__ W,
    float* __restrict__ out, uint4* __restrict__ spec)
{
    __shared__ float2 lut2[16];
    const float w1 = W[0], w2 = W[1], w12 = __fadd_rn(w1, w2);
    lut_init(lut2, w1, w2, w12);
    __syncthreads();
    scanA_item(codes, out, spec, lut2, blockIdx.x * 256 + threadIdx.x);
}

__global__ __launch_bounds__(64) void fmfm_scanB(
    const uint32_t* __restrict__ codes, const float* __restrict__ W,
    float* __restrict__ out, const uint4* __restrict__ spec)
{
    const float w1 = W[0], w2 = W[1], w12 = __fadd_rn(w1, w2);
    scanB_item(codes, w1, w2, w12, out, spec, blockIdx.x * 64 + threadIdx.x);
}

// round-1 proven fused fallback (if ws too small)
__global__ __launch_bounds__(64) void fmfm_scan_fused(
    const float2* __restrict__ sp, const float* __restrict__ W,
    float* __restrict__ out)
{
    const int b = blockIdx.x * 64 + threadIdx.x;
    const float w1 = W[0];
    const float w2 = W[1];
    const float2* p = sp + b;
    float* q = out + b;
    float mem = 0.0f, rst = 0.0f;
    #pragma unroll 8
    for (int t = 0; t < T_STEPS; ++t) {
        float2 s = p[(size_t)t * B_NEUR];
        float cur = __fadd_rn(__fmul_rn(s.x, w1), __fmul_rn(s.y, w2));
        float m = __fsub_rn(__fadd_rn(__fmul_rn(0.95f, mem), cur), rst);
        float spk = (m > 1.0f) ? 1.0f : 0.0f;
        q[(size_t)t * B_NEUR] = spk;
        mem = m;
        rst = spk;
    }
}

extern "C" void kernel_launch(void* const* d_in, const int* in_sizes, int n_in,
                              void* d_out, int out_size, void* d_ws, size_t ws_size,
                              hipStream_t stream) {
    const f4v*   sp4 = (const f4v*)d_in[0];
    const float* W   = (const float*)d_in[1];
    float*       out = (float*)d_out;

    const size_t codes_bytes = (size_t)KG * B_NEUR * 4;          // 4MB
    const size_t spec_bytes  = (size_t)NCHUNK * B_NEUR * 16;     // 1MB
    if (ws_size < codes_bytes + spec_bytes) {
        fmfm_scan_fused<<<dim3(B_NEUR / 64), dim3(64), 0, stream>>>(
            (const float2*)d_in[0], W, out);
        return;
    }
    uint32_t* codes = (uint32_t*)d_ws;
    uint4*    spec  = (uint4*)((char*)d_ws + codes_bytes);

    void* args[] = {(void*)&sp4, (void*)&W, (void*)&out,
                    (void*)&codes, (void*)&spec};
    hipError_t e = hipLaunchCooperativeKernel(
        (const void*)fmfm_mega, dim3(256), dim3(256), args, 0u, stream);
    if (e == hipSuccess) return;

    // fallback: proven 3-kernel path
    fmfm_compress<<<dim3(KG * (B_NEUR / 2) / 256), dim3(256), 0, stream>>>(sp4, codes);
    fmfm_scanA<<<dim3(NCHUNK * B_NEUR / 256), dim3(256), 0, stream>>>(codes, W, out, spec);
    fmfm_scanB<<<dim3(B_NEUR / 64), dim3(64), 0, stream>>>(codes, W, out, spec);
}

// Round 11
// 141.670 us; speedup vs baseline: 1.2955x; 1.2955x over previous
//
#include <hip/hip_runtime.h>
#include <stdint.h>

// FMFMNeuron LIF scan — 2 kernels (r9 structure, scanB merged into scanA):
//  K1 compress: 134MB f32 spikes -> 4MB 2-bit cur-codes [T/16][B] (nt loads);
//     also resets the completion ticket counter.
//  K2 scanAB: C=16 chunks x B neurons; 768-step warmup from mem=0 (chunks
//     0..2 clamped => exact), 256-step body writes f32 spikes to out (nt
//     stores) + (start,end) state to spec[]. Then last-finishing block
//     (atomic ticket + threadfence acquire) chains chunks: bit-compare true
//     state vs spec start; match -> adopt end; mismatch -> recompute chunk
//     exactly + patch out. Bit-exact REGARDLESS of speculation quality.
//
// Step math (absmax=0, rounds 1..10): spikes in {0,1} =>
//   cur in {0, w1, w2, fadd(w1,w2)} exactly; strict left-to-right:
//   m = fsub(fadd(fmul(0.95f,mem), cur), rst); spk = m>1.0f; rst' = spk.

#define T_STEPS 4096
#define B_NEUR  4096
#define NCHUNK  16
#define CH_W    16                     // code words per chunk body
#define WARM_W  48                     // warmup words (768 steps)
#define KG      (T_STEPS / 16)         // 256 code words per neuron

typedef float f4v __attribute__((ext_vector_type(4)));

// ---- K1: compress spikes to 2-bit codes + reset ticket ---------------------
__global__ __launch_bounds__(256) void fmfm_compress(
    const f4v*  __restrict__ sp4,      // [T][B/2] float4
    uint32_t*   __restrict__ codes,    // [T/16][B]
    uint32_t*   __restrict__ ticket)
{
    if (blockIdx.x == 0 && threadIdx.x == 0) *ticket = 0;
    const int tid = blockIdx.x * 256 + threadIdx.x;   // 0 .. 512K-1
    const int b2  = tid & (B_NEUR / 2 - 1);           // neuron pair
    const int kg  = tid >> 11;                        // 0..255
    const f4v* p = sp4 + (size_t)kg * 16 * (B_NEUR / 2) + b2;
    uint32_t we = 0, wo = 0;
    #pragma unroll
    for (int i = 0; i < 16; ++i) {
        f4v s = __builtin_nontemporal_load(p + (size_t)i * (B_NEUR / 2));
        uint32_t ce = (s.x != 0.0f ? 1u : 0u) | (s.y != 0.0f ? 2u : 0u);
        uint32_t co = (s.z != 0.0f ? 1u : 0u) | (s.w != 0.0f ? 2u : 0u);
        we |= ce << (2 * i);
        wo |= co << (2 * i);
    }
    *reinterpret_cast<uint2*>(codes + (size_t)kg * B_NEUR + 2 * b2) =
        make_uint2(we, wo);
}

// ---- K2: speculative chunk scan + last-block exact chaining ----------------
__global__ __launch_bounds__(256) void fmfm_scanAB(
    const uint32_t* __restrict__ codes,    // [T/16][B]
    const float*    __restrict__ W,
    float*          __restrict__ out,      // [T][B]
    uint4*          __restrict__ spec,     // [C][B]: start/end states
    uint32_t*       __restrict__ ticket)
{
    __shared__ float2 lut2[16];   // nibble -> 2 exact cur values
    __shared__ int is_last;

    const float w1  = W[0];
    const float w2  = W[1];
    const float w12 = __fadd_rn(w1, w2);

    if (threadIdx.x < 16) {
        uint32_t e = threadIdx.x;
        uint32_t c0 = e & 3u, c1 = (e >> 2) & 3u;
        float2 v;
        v.x = (c0 & 1u) ? ((c0 & 2u) ? w12 : w1) : ((c0 & 2u) ? w2 : 0.0f);
        v.y = (c1 & 1u) ? ((c1 & 2u) ? w12 : w1) : ((c1 & 2u) ? w2 : 0.0f);
        lut2[e] = v;
    }
    __syncthreads();

    const int tid = blockIdx.x * 256 + threadIdx.x;   // 0..65535
    const int b   = tid & (B_NEUR - 1);
    const int c   = tid >> 12;                        // chunk 0..15
    const int body_w0 = c * CH_W;
    const int w_start = (body_w0 >= WARM_W) ? body_w0 - WARM_W : 0;
    const int w_end   = body_w0 + CH_W;
    const uint32_t* cp = codes + b;

#define CLD(IDX) cp[(size_t)((IDX) < w_end ? (IDX) : (w_end - 1)) * B_NEUR]
#define DECODE2(WORD, D)                                                  \
    {                                                                     \
        _Pragma("unroll")                                                 \
        for (int _j = 0; _j < 8; ++_j)                                    \
            D[_j] = lut2[((WORD) >> (4 * _j)) & 0xFu];                    \
    }
#define STEPN(CUR)                                                        \
    {                                                                     \
        float _m = __fsub_rn(__fadd_rn(__fmul_rn(0.95f, mem), (CUR)),     \
                             rst);                                        \
        rst = (_m > 1.0f) ? 1.0f : 0.0f;                                  \
        mem = _m;                                                         \
    }
#define STEPS_(CUR, Q, K)                                                 \
    {                                                                     \
        float _m = __fsub_rn(__fadd_rn(__fmul_rn(0.95f, mem), (CUR)),     \
                             rst);                                        \
        rst = (_m > 1.0f) ? 1.0f : 0.0f;                                  \
        mem = _m;                                                         \
        __builtin_nontemporal_store(rst, (Q) + (size_t)(K) * B_NEUR);     \
    }
#define CHAIN16N(D)                                                       \
    {                                                                     \
        _Pragma("unroll")                                                 \
        for (int _j = 0; _j < 8; ++_j) { STEPN(D[_j].x) STEPN(D[_j].y) }  \
    }
#define CHAIN16S(D, WIDX)                                                 \
    {                                                                     \
        float* _q = out + (size_t)(WIDX) * 16 * B_NEUR + b;               \
        _Pragma("unroll")                                                 \
        for (int _j = 0; _j < 8; ++_j) {                                  \
            STEPS_(D[_j].x, _q, 2 * _j)                                   \
            STEPS_(D[_j].y, _q, 2 * _j + 1)                               \
        }                                                                 \
    }

    uint32_t pa = CLD(w_start);
    uint32_t pb = CLD(w_start + 1);
    uint32_t pc = CLD(w_start + 2);
    uint32_t pd = CLD(w_start + 3);

    float2 dA[8], dB[8];
    DECODE2(pa, dA)

    float mem = 0.0f, rst = 0.0f;

    for (int iw = w_start; iw < body_w0; iw += 2) {   // warmup, no stores
        uint32_t t0 = CLD(iw + 4);
        DECODE2(pb, dB)
        CHAIN16N(dA)
        pa = pb; pb = pc; pc = pd; pd = t0;
        uint32_t t1 = CLD(iw + 5);
        DECODE2(pb, dA)
        CHAIN16N(dB)
        pa = pb; pb = pc; pc = pd; pd = t1;
    }

    const float sm = mem;
    const float sr = rst;

    for (int iw = body_w0; iw < w_end; iw += 2) {     // body, nt stores
        uint32_t t0 = CLD(iw + 4);
        DECODE2(pb, dB)
        CHAIN16S(dA, iw)
        pa = pb; pb = pc; pc = pd; pd = t0;
        uint32_t t1 = CLD(iw + 5);
        DECODE2(pb, dA)
        CHAIN16S(dB, iw + 1)
        pa = pb; pb = pc; pc = pd; pd = t1;
    }

    uint4 sv;
    sv.x = __float_as_uint(sm);
    sv.y = (sr != 0.0f) ? 1u : 0u;
    sv.z = __float_as_uint(mem);
    sv.w = (rst != 0.0f) ? 1u : 0u;
    spec[(size_t)c * B_NEUR + b] = sv;

    // ---- last-block completion: exact chaining / patch ----
    __threadfence();                       // release: spec + out visible
    __syncthreads();
    if (threadIdx.x == 0)
        is_last = (atomicAdd(ticket, 1u) == (uint32_t)(gridDim.x - 1));
    __syncthreads();
    if (!is_last) return;
    __threadfence();                       // acquire: see all blocks' spec

    for (int n = threadIdx.x; n < B_NEUR; n += 256) {
        float vmem = 0.0f, vrst = 0.0f;
        uint4 sn = spec[n];
        for (int cc2 = 0; cc2 < NCHUNK; ++cc2) {
            uint4 s = sn;
            if (cc2 + 1 < NCHUNK) sn = spec[(size_t)(cc2 + 1) * B_NEUR + n];
            bool ok = (s.x == __float_as_uint(vmem)) &&
                      ((s.y != 0u) == (vrst != 0.0f));
            if (ok) {
                vmem = __uint_as_float(s.z);
                vrst = s.w ? 1.0f : 0.0f;
            } else {
                // rare: recompute chunk exactly from true state, patch out
                for (int wi = 0; wi < CH_W; ++wi) {
                    uint32_t w = codes[(size_t)(cc2 * CH_W + wi) * B_NEUR + n];
                    float* q = out + (size_t)(cc2 * CH_W + wi) * 16 * B_NEUR + n;
                    #pragma unroll
                    for (int j = 0; j < 16; ++j) {
                        uint32_t cj = (w >> (2 * j)) & 3u;
                        float cur = (cj & 1u) ? ((cj & 2u) ? w12 : w1)
                                              : ((cj & 2u) ? w2 : 0.0f);
                        float m = __fsub_rn(
                            __fadd_rn(__fmul_rn(0.95f, vmem), cur), vrst);
                        vrst = (m > 1.0f) ? 1.0f : 0.0f;
                        vmem = m;
                        q[(size_t)j * B_NEUR] = vrst;
                    }
                }
            }
        }
    }

#undef CLD
#undef DECODE2
#undef STEPN
#undef STEPS_
#undef CHAIN16N
#undef CHAIN16S
}

// ---- fallback: round-1 proven fused kernel (if ws too small) ---------------
__global__ __launch_bounds__(64) void fmfm_scan_fused(
    const float2* __restrict__ sp, const float* __restrict__ W,
    float* __restrict__ out)
{
    const int b = blockIdx.x * 64 + threadIdx.x;
    const float w1 = W[0];
    const float w2 = W[1];
    const float2* p = sp + b;
    float* q = out + b;
    float mem = 0.0f, rst = 0.0f;
    #pragma unroll 8
    for (int t = 0; t < T_STEPS; ++t) {
        float2 s = p[(size_t)t * B_NEUR];
        float cur = __fadd_rn(__fmul_rn(s.x, w1), __fmul_rn(s.y, w2));
        float m = __fsub_rn(__fadd_rn(__fmul_rn(0.95f, mem), cur), rst);
        float spk = (m > 1.0f) ? 1.0f : 0.0f;
        q[(size_t)t * B_NEUR] = spk;
        mem = m;
        rst = spk;
    }
}

extern "C" void kernel_launch(void* const* d_in, const int* in_sizes, int n_in,
                              void* d_out, int out_size, void* d_ws, size_t ws_size,
                              hipStream_t stream) {
    const f4v*   sp4 = (const f4v*)d_in[0];
    const float* W   = (const float*)d_in[1];
    float*       out = (float*)d_out;

    const size_t codes_bytes = (size_t)KG * B_NEUR * 4;          // 4MB
    const size_t spec_bytes  = (size_t)NCHUNK * B_NEUR * 16;     // 1MB
    if (ws_size < codes_bytes + spec_bytes + 64) {
        fmfm_scan_fused<<<dim3(B_NEUR / 64), dim3(64), 0, stream>>>(
            (const float2*)d_in[0], W, out);
        return;
    }
    uint32_t* codes  = (uint32_t*)d_ws;
    uint4*    spec   = (uint4*)((char*)d_ws + codes_bytes);
    uint32_t* ticket = (uint32_t*)((char*)d_ws + codes_bytes + spec_bytes);

    fmfm_compress<<<dim3(KG * (B_NEUR / 2) / 256), dim3(256), 0, stream>>>(
        sp4, codes, ticket);
    fmfm_scanAB<<<dim3(NCHUNK * B_NEUR / 256), dim3(256), 0, stream>>>(
        codes, W, out, spec, ticket);
}

// Round 12
// 60.210 us; speedup vs baseline: 3.0482x; 2.3529x over previous
//
#include <hip/hip_runtime.h>
#include <stdint.h>

// FMFMNeuron LIF scan, 3-phase with EXACT speculative T-chunking (r9 structure,
// chunk geometry retuned for 2 waves/SIMD):
//  1) compress: 134MB f32 spikes -> 4MB 2-bit cur-codes [T/16][B] (nt loads)
//  2) scanA: C=32 chunks x B neurons (512 blocks = 2 waves/SIMD — hides the
//     67MB store burst that serialized the C=16 version at 1 wave/SIMD).
//     768-step warmup from mem=0 (chunks 0..5 clamped to t=0 => exact), then
//     128-step body writing f32 spikes DIRECTLY to out (nt stores) +
//     (start,end) states to spec[].
//  3) scanB: chain chunks by bit-comparing true state vs spec start;
//     match -> adopt spec end; mismatch -> recompute chunk exactly, patch out.
//     Output is bit-exact REGARDLESS of speculation quality.
//
// Step math (absmax=0 through rounds 1..11): spikes in {0,1} =>
//   cur in {0, w1, w2, fadd(w1,w2)} exactly; strict left-to-right:
//   m = fsub(fadd(fmul(0.95f,mem), cur), rst); spk = m>1.0f; rst' = spk.

#define T_STEPS 4096
#define B_NEUR  4096
#define NCHUNK  32
#define CH_W    8                      // code words per chunk body (128 steps)
#define WARM_W  48                     // warmup words (768 steps)
#define KG      (T_STEPS / 16)         // 256 code words per neuron

typedef float f4v __attribute__((ext_vector_type(4)));

// ---- phase 1: compress spikes to 2-bit codes (nt float4 loads) -------------
__global__ __launch_bounds__(256) void fmfm_compress(
    const f4v*  __restrict__ sp4,      // [T][B/2] float4
    uint32_t*   __restrict__ codes)    // [T/16][B]
{
    const int tid = blockIdx.x * 256 + threadIdx.x;   // 0 .. 512K-1
    const int b2  = tid & (B_NEUR / 2 - 1);           // neuron pair
    const int kg  = tid >> 11;                        // 0..255
    const f4v* p = sp4 + (size_t)kg * 16 * (B_NEUR / 2) + b2;
    uint32_t we = 0, wo = 0;
    #pragma unroll
    for (int i = 0; i < 16; ++i) {
        f4v s = __builtin_nontemporal_load(p + (size_t)i * (B_NEUR / 2));
        uint32_t ce = (s.x != 0.0f ? 1u : 0u) | (s.y != 0.0f ? 2u : 0u);
        uint32_t co = (s.z != 0.0f ? 1u : 0u) | (s.w != 0.0f ? 2u : 0u);
        we |= ce << (2 * i);
        wo |= co << (2 * i);
    }
    *reinterpret_cast<uint2*>(codes + (size_t)kg * B_NEUR + 2 * b2) =
        make_uint2(we, wo);
}

// ---- phase 2: parallel speculative chunk scan, direct f32 output -----------
__global__ __launch_bounds__(256) void fmfm_scanA(
    const uint32_t* __restrict__ codes,    // [T/16][B]
    const float*    __restrict__ W,
    float*          __restrict__ out,      // [T][B]
    uint4*          __restrict__ spec)     // [C][B]: start/end states
{
    __shared__ float2 lut2[16];   // nibble -> 2 exact cur values

    const float w1  = W[0];
    const float w2  = W[1];
    const float w12 = __fadd_rn(w1, w2);

    if (threadIdx.x < 16) {
        uint32_t e = threadIdx.x;
        uint32_t c0 = e & 3u, c1 = (e >> 2) & 3u;
        float2 v;
        v.x = (c0 & 1u) ? ((c0 & 2u) ? w12 : w1) : ((c0 & 2u) ? w2 : 0.0f);
        v.y = (c1 & 1u) ? ((c1 & 2u) ? w12 : w1) : ((c1 & 2u) ? w2 : 0.0f);
        lut2[e] = v;
    }
    __syncthreads();

    const int tid = blockIdx.x * 256 + threadIdx.x;   // 0..131071
    const int b   = tid & (B_NEUR - 1);
    const int c   = tid >> 12;                        // chunk 0..31
    const int body_w0 = c * CH_W;
    const int w_start = (body_w0 >= WARM_W) ? body_w0 - WARM_W : 0;
    const int w_end   = body_w0 + CH_W;               // exclusive
    const uint32_t* cp = codes + b;

#define CLD(IDX) cp[(size_t)((IDX) < w_end ? (IDX) : (w_end - 1)) * B_NEUR]
#define DECODE2(WORD, D)                                                  \
    {                                                                     \
        _Pragma("unroll")                                                 \
        for (int _j = 0; _j < 8; ++_j)                                    \
            D[_j] = lut2[((WORD) >> (4 * _j)) & 0xFu];                    \
    }
#define STEPN(CUR)                                                        \
    {                                                                     \
        float _m = __fsub_rn(__fadd_rn(__fmul_rn(0.95f, mem), (CUR)),     \
                             rst);                                        \
        rst = (_m > 1.0f) ? 1.0f : 0.0f;                                  \
        mem = _m;                                                         \
    }
#define STEPS_(CUR, Q, K)                                                 \
    {                                                                     \
        float _m = __fsub_rn(__fadd_rn(__fmul_rn(0.95f, mem), (CUR)),     \
                             rst);                                        \
        rst = (_m > 1.0f) ? 1.0f : 0.0f;                                  \
        mem = _m;                                                         \
        __builtin_nontemporal_store(rst, (Q) + (size_t)(K) * B_NEUR);     \
    }
#define CHAIN16N(D)                                                       \
    {                                                                     \
        _Pragma("unroll")                                                 \
        for (int _j = 0; _j < 8; ++_j) { STEPN(D[_j].x) STEPN(D[_j].y) }  \
    }
#define CHAIN16S(D, WIDX)                                                 \
    {                                                                     \
        float* _q = out + (size_t)(WIDX) * 16 * B_NEUR + b;               \
        _Pragma("unroll")                                                 \
        for (int _j = 0; _j < 8; ++_j) {                                  \
            STEPS_(D[_j].x, _q, 2 * _j)                                   \
            STEPS_(D[_j].y, _q, 2 * _j + 1)                               \
        }                                                                 \
    }

    uint32_t pa = CLD(w_start);
    uint32_t pb = CLD(w_start + 1);
    uint32_t pc = CLD(w_start + 2);
    uint32_t pd = CLD(w_start + 3);

    float2 dA[8], dB[8];
    DECODE2(pa, dA)

    float mem = 0.0f, rst = 0.0f;

    // warmup: no stores (trip 0 for chunks 0..; clamped => exact for c*8<48)
    for (int iw = w_start; iw < body_w0; iw += 2) {
        uint32_t t0 = CLD(iw + 4);
        DECODE2(pb, dB)
        CHAIN16N(dA)
        pa = pb; pb = pc; pc = pd; pd = t0;
        uint32_t t1 = CLD(iw + 5);
        DECODE2(pb, dA)
        CHAIN16N(dB)
        pa = pb; pb = pc; pc = pd; pd = t1;
    }

    const float sm = mem;
    const float sr = rst;

    // body: direct nt stores of spike floats
    for (int iw = body_w0; iw < w_end; iw += 2) {
        uint32_t t0 = CLD(iw + 4);
        DECODE2(pb, dB)
        CHAIN16S(dA, iw)
        pa = pb; pb = pc; pc = pd; pd = t0;
        uint32_t t1 = CLD(iw + 5);
        DECODE2(pb, dA)
        CHAIN16S(dB, iw + 1)
        pa = pb; pb = pc; pc = pd; pd = t1;
    }

    uint4 sv;
    sv.x = __float_as_uint(sm);
    sv.y = (sr != 0.0f) ? 1u : 0u;
    sv.z = __float_as_uint(mem);
    sv.w = (rst != 0.0f) ? 1u : 0u;
    spec[(size_t)c * B_NEUR + b] = sv;

#undef CLD
#undef DECODE2
#undef STEPN
#undef STEPS_
#undef CHAIN16N
#undef CHAIN16S
}

// ---- phase 3: exact chaining / verification, patches f32 out ---------------
__global__ __launch_bounds__(64) void fmfm_scanB(
    const uint32_t* __restrict__ codes,
    const float*    __restrict__ W,
    float*          __restrict__ out,
    const uint4*    __restrict__ spec)
{
    const int b = blockIdx.x * 64 + threadIdx.x;
    const float w1  = W[0];
    const float w2  = W[1];
    const float w12 = __fadd_rn(w1, w2);

    float mem = 0.0f, rst = 0.0f;
    uint4 sn = spec[b];
    for (int c = 0; c < NCHUNK; ++c) {
        uint4 s = sn;
        if (c + 1 < NCHUNK) sn = spec[(size_t)(c + 1) * B_NEUR + b];
        bool ok = (s.x == __float_as_uint(mem)) &&
                  ((s.y != 0u) == (rst != 0.0f));
        if (ok) {
            mem = __uint_as_float(s.z);
            rst = s.w ? 1.0f : 0.0f;
        } else {
            // rare: recompute chunk c exactly from true state, patch out
            for (int wi = 0; wi < CH_W; ++wi) {
                uint32_t w = codes[(size_t)(c * CH_W + wi) * B_NEUR + b];
                float* q = out + (size_t)(c * CH_W + wi) * 16 * B_NEUR + b;
                #pragma unroll
                for (int j = 0; j < 16; ++j) {
                    uint32_t cc = (w >> (2 * j)) & 3u;
                    float cur = (cc & 1u) ? ((cc & 2u) ? w12 : w1)
                                          : ((cc & 2u) ? w2 : 0.0f);
                    float m = __fsub_rn(__fadd_rn(__fmul_rn(0.95f, mem), cur),
                                        rst);
                    rst = (m > 1.0f) ? 1.0f : 0.0f;
                    mem = m;
                    q[(size_t)j * B_NEUR] = rst;
                }
            }
        }
    }
}

// ---- fallback: round-1 proven fused kernel (if ws too small) ---------------
__global__ __launch_bounds__(64) void fmfm_scan_fused(
    const float2* __restrict__ sp, const float* __restrict__ W,
    float* __restrict__ out)
{
    const int b = blockIdx.x * 64 + threadIdx.x;
    const float w1 = W[0];
    const float w2 = W[1];
    const float2* p = sp + b;
    float* q = out + b;
    float mem = 0.0f, rst = 0.0f;
    #pragma unroll 8
    for (int t = 0; t < T_STEPS; ++t) {
        float2 s = p[(size_t)t * B_NEUR];
        float cur = __fadd_rn(__fmul_rn(s.x, w1), __fmul_rn(s.y, w2));
        float m = __fsub_rn(__fadd_rn(__fmul_rn(0.95f, mem), cur), rst);
        float spk = (m > 1.0f) ? 1.0f : 0.0f;
        q[(size_t)t * B_NEUR] = spk;
        mem = m;
        rst = spk;
    }
}

extern "C" void kernel_launch(void* const* d_in, const int* in_sizes, int n_in,
                              void* d_out, int out_size, void* d_ws, size_t ws_size,
                              hipStream_t stream) {
    const f4v*   sp4 = (const f4v*)d_in[0];
    const float* W   = (const float*)d_in[1];
    float*       out = (float*)d_out;

    const size_t codes_bytes = (size_t)KG * B_NEUR * 4;          // 4MB
    const size_t spec_bytes  = (size_t)NCHUNK * B_NEUR * 16;     // 2MB
    if (ws_size < codes_bytes + spec_bytes) {
        fmfm_scan_fused<<<dim3(B_NEUR / 64), dim3(64), 0, stream>>>(
            (const float2*)d_in[0], W, out);
        return;
    }
    uint32_t* codes = (uint32_t*)d_ws;
    uint4*    spec  = (uint4*)((char*)d_ws + codes_bytes);

    fmfm_compress<<<dim3(KG * (B_NEUR / 2) / 256), dim3(256), 0, stream>>>(sp4, codes);
    fmfm_scanA<<<dim3(NCHUNK * B_NEUR / 256), dim3(256), 0, stream>>>(codes, W, out, spec);
    fmfm_scanB<<<dim3(B_NEUR / 64), dim3(64), 0, stream>>>(codes, W, out, spec);
}

// Round 13
// 58.042 us; speedup vs baseline: 3.1621x; 1.0373x over previous
//
#include <hip/hip_runtime.h>
#include <stdint.h>

// FMFMNeuron LIF scan, 3-phase with EXACT speculative T-chunking (r9 geometry;
// scanA output path reworked: bits -> LDS -> coalesced float4 stores):
//  1) compress: 134MB f32 spikes -> 4MB 2-bit cur-codes [T/16][B] (nt loads)
//  2) scanA: C=16 chunks x B neurons; 768-step warmup from mem=0 (chunks 0..2
//     clamped => exact). Body: accumulate 32-step spike bits in a register,
//     dump to LDS (1KB), block-transpose-expand to f32 with float4 stores
//     (replaces r9's 4B nt scalar stores which measured ~2.8 TB/s).
//  3) scanB: chain chunks by bit-comparing true state vs spec start; match ->
//     adopt spec end; mismatch -> recompute chunk exactly, patch out.
//     Output is bit-exact REGARDLESS of speculation quality.
//
// Step math (absmax=0 through rounds 1..12): spikes in {0,1} =>
//   cur in {0, w1, w2, fadd(w1,w2)} exactly; strict left-to-right:
//   m = fsub(fadd(fmul(0.95f,mem), cur), rst); spk = m>1.0f; rst' = spk.

#define T_STEPS 4096
#define B_NEUR  4096
#define NCHUNK  16
#define CH_W    16                     // code words per chunk body (256 steps)
#define WARM_W  48                     // warmup words (768 steps)
#define KG      (T_STEPS / 16)         // 256 code words per neuron

typedef float f4v __attribute__((ext_vector_type(4)));

// ---- phase 1: compress spikes to 2-bit codes (nt float4 loads) -------------
__global__ __launch_bounds__(256) void fmfm_compress(
    const f4v*  __restrict__ sp4,      // [T][B/2] float4
    uint32_t*   __restrict__ codes)    // [T/16][B]
{
    const int tid = blockIdx.x * 256 + threadIdx.x;   // 0 .. 512K-1
    const int b2  = tid & (B_NEUR / 2 - 1);           // neuron pair
    const int kg  = tid >> 11;                        // 0..255
    const f4v* p = sp4 + (size_t)kg * 16 * (B_NEUR / 2) + b2;
    uint32_t we = 0, wo = 0;
    #pragma unroll
    for (int i = 0; i < 16; ++i) {
        f4v s = __builtin_nontemporal_load(p + (size_t)i * (B_NEUR / 2));
        uint32_t ce = (s.x != 0.0f ? 1u : 0u) | (s.y != 0.0f ? 2u : 0u);
        uint32_t co = (s.z != 0.0f ? 1u : 0u) | (s.w != 0.0f ? 2u : 0u);
        we |= ce << (2 * i);
        wo |= co << (2 * i);
    }
    *reinterpret_cast<uint2*>(codes + (size_t)kg * B_NEUR + 2 * b2) =
        make_uint2(we, wo);
}

// ---- phase 2: parallel speculative chunk scan, transposed f4 output --------
__global__ __launch_bounds__(256) void fmfm_scanA(
    const uint32_t* __restrict__ codes,    // [T/16][B]
    const float*    __restrict__ W,
    float*          __restrict__ out,      // [T][B]
    uint4*          __restrict__ spec)     // [C][B]: start/end states
{
    __shared__ float2   lut2[16];       // nibble -> 2 exact cur values
    __shared__ uint32_t lbits[256];     // one 32-step word of spike bits

    const float w1  = W[0];
    const float w2  = W[1];
    const float w12 = __fadd_rn(w1, w2);

    if (threadIdx.x < 16) {
        uint32_t e = threadIdx.x;
        uint32_t c0 = e & 3u, c1 = (e >> 2) & 3u;
        float2 v;
        v.x = (c0 & 1u) ? ((c0 & 2u) ? w12 : w1) : ((c0 & 2u) ? w2 : 0.0f);
        v.y = (c1 & 1u) ? ((c1 & 2u) ? w12 : w1) : ((c1 & 2u) ? w2 : 0.0f);
        lut2[e] = v;
    }
    __syncthreads();

    const int tid = blockIdx.x * 256 + threadIdx.x;   // 0..65535
    const int b   = tid & (B_NEUR - 1);
    const int c   = tid >> 12;                        // chunk 0..15 (block-uniform)
    const int b0  = (blockIdx.x * 256) & (B_NEUR - 1);// block's neuron base
    const int body_w0 = c * CH_W;
    const int w_start = (body_w0 >= WARM_W) ? body_w0 - WARM_W : 0;
    const int w_end   = body_w0 + CH_W;               // exclusive
    const uint32_t* cp = codes + b;

#define CLD(IDX) cp[(size_t)((IDX) < w_end ? (IDX) : (w_end - 1)) * B_NEUR]
#define DECODE2(WORD, D)                                                  \
    {                                                                     \
        _Pragma("unroll")                                                 \
        for (int _j = 0; _j < 8; ++_j)                                    \
            D[_j] = lut2[((WORD) >> (4 * _j)) & 0xFu];                    \
    }
#define STEPN(CUR)                                                        \
    {                                                                     \
        float _m = __fsub_rn(__fadd_rn(__fmul_rn(0.95f, mem), (CUR)),     \
                             rst);                                        \
        rst = (_m > 1.0f) ? 1.0f : 0.0f;                                  \
        mem = _m;                                                         \
    }
#define STEPB(CUR, POS)                                                   \
    {                                                                     \
        float _m = __fsub_rn(__fadd_rn(__fmul_rn(0.95f, mem), (CUR)),     \
                             rst);                                        \
        uint32_t _sb = (_m > 1.0f) ? 1u : 0u;                             \
        bits |= _sb << (POS);                                             \
        rst = _sb ? 1.0f : 0.0f;                                          \
        mem = _m;                                                         \
    }
#define CHAIN16N(D)                                                       \
    {                                                                     \
        _Pragma("unroll")                                                 \
        for (int _j = 0; _j < 8; ++_j) { STEPN(D[_j].x) STEPN(D[_j].y) }  \
    }
#define CHAIN16B(D, HALF)                                                 \
    {                                                                     \
        _Pragma("unroll")                                                 \
        for (int _j = 0; _j < 8; ++_j) {                                  \
            STEPB(D[_j].x, ((HALF) << 4) + 2 * _j)                        \
            STEPB(D[_j].y, ((HALF) << 4) + 2 * _j + 1)                    \
        }                                                                 \
    }

    uint32_t pa = CLD(w_start);
    uint32_t pb = CLD(w_start + 1);
    uint32_t pc = CLD(w_start + 2);
    uint32_t pd = CLD(w_start + 3);

    float2 dA[8], dB[8];
    DECODE2(pa, dA)

    float mem = 0.0f, rst = 0.0f;

    // warmup: no stores (trip count 0 for chunk 0)
    for (int iw = w_start; iw < body_w0; iw += 2) {
        uint32_t t0 = CLD(iw + 4);
        DECODE2(pb, dB)
        CHAIN16N(dA)
        pa = pb; pb = pc; pc = pd; pd = t0;
        uint32_t t1 = CLD(iw + 5);
        DECODE2(pb, dA)
        CHAIN16N(dB)
        pa = pb; pb = pc; pc = pd; pd = t1;
    }

    const float sm = mem;
    const float sr = rst;

    // body: accumulate 32-step bit words; expand via LDS to float4 stores
    const int q  = threadIdx.x & 63;       // column group (4 neurons)
    const int th = threadIdx.x >> 6;       // t-octet 0..3
    for (int iw = body_w0; iw < w_end; iw += 2) {
        uint32_t bits = 0;
        uint32_t t0 = CLD(iw + 4);
        DECODE2(pb, dB)
        CHAIN16B(dA, 0)
        pa = pb; pb = pc; pc = pd; pd = t0;
        uint32_t t1 = CLD(iw + 5);
        DECODE2(pb, dA)
        CHAIN16B(dB, 1)
        pa = pb; pb = pc; pc = pd; pd = t1;

        lbits[threadIdx.x] = bits;
        __syncthreads();
        // expand 32t x 256b tile: thread handles rows th*8..th*8+7 of col 4q
        const uint4 bw = *reinterpret_cast<const uint4*>(&lbits[4 * q]);
        float* qp = out + (size_t)iw * 16 * B_NEUR + b0 + 4 * q;
        #pragma unroll
        for (int r = 0; r < 8; ++r) {
            const int tp = th * 8 + r;      // 0..31
            f4v v;
            v.x = ((bw.x >> tp) & 1u) ? 1.0f : 0.0f;
            v.y = ((bw.y >> tp) & 1u) ? 1.0f : 0.0f;
            v.z = ((bw.z >> tp) & 1u) ? 1.0f : 0.0f;
            v.w = ((bw.w >> tp) & 1u) ? 1.0f : 0.0f;
            *reinterpret_cast<f4v*>(qp + (size_t)tp * B_NEUR) = v;
        }
        __syncthreads();
    }

    uint4 sv;
    sv.x = __float_as_uint(sm);
    sv.y = (sr != 0.0f) ? 1u : 0u;
    sv.z = __float_as_uint(mem);
    sv.w = (rst != 0.0f) ? 1u : 0u;
    spec[(size_t)c * B_NEUR + b] = sv;

#undef CLD
#undef DECODE2
#undef STEPN
#undef STEPB
#undef CHAIN16N
#undef CHAIN16B
}

// ---- phase 3: exact chaining / verification, patches f32 out ---------------
__global__ __launch_bounds__(64) void fmfm_scanB(
    const uint32_t* __restrict__ codes,
    const float*    __restrict__ W,
    float*          __restrict__ out,
    const uint4*    __restrict__ spec)
{
    const int b = blockIdx.x * 64 + threadIdx.x;
    const float w1  = W[0];
    const float w2  = W[1];
    const float w12 = __fadd_rn(w1, w2);

    float mem = 0.0f, rst = 0.0f;
    uint4 sn = spec[b];
    for (int c = 0; c < NCHUNK; ++c) {
        uint4 s = sn;
        if (c + 1 < NCHUNK) sn = spec[(size_t)(c + 1) * B_NEUR + b];
        bool ok = (s.x == __float_as_uint(mem)) &&
                  ((s.y != 0u) == (rst != 0.0f));
        if (ok) {
            mem = __uint_as_float(s.z);
            rst = s.w ? 1.0f : 0.0f;
        } else {
            // rare: recompute chunk c exactly from true state, patch out
            for (int wi = 0; wi < CH_W; ++wi) {
                uint32_t w = codes[(size_t)(c * CH_W + wi) * B_NEUR + b];
                float* q = out + (size_t)(c * CH_W + wi) * 16 * B_NEUR + b;
                #pragma unroll
                for (int j = 0; j < 16; ++j) {
                    uint32_t cc = (w >> (2 * j)) & 3u;
                    float cur = (cc & 1u) ? ((cc & 2u) ? w12 : w1)
                                          : ((cc & 2u) ? w2 : 0.0f);
                    float m = __fsub_rn(__fadd_rn(__fmul_rn(0.95f, mem), cur),
                                        rst);
                    rst = (m > 1.0f) ? 1.0f : 0.0f;
                    mem = m;
                    q[(size_t)j * B_NEUR] = rst;
                }
            }
        }
    }
}

// ---- fallback: round-1 proven fused kernel (if ws too small) ---------------
__global__ __launch_bounds__(64) void fmfm_scan_fused(
    const float2* __restrict__ sp, const float* __restrict__ W,
    float* __restrict__ out)
{
    const int b = blockIdx.x * 64 + threadIdx.x;
    const float w1 = W[0];
    const float w2 = W[1];
    const float2* p = sp + b;
    float* q = out + b;
    float mem = 0.0f, rst = 0.0f;
    #pragma unroll 8
    for (int t = 0; t < T_STEPS; ++t) {
        float2 s = p[(size_t)t * B_NEUR];
        float cur = __fadd_rn(__fmul_rn(s.x, w1), __fmul_rn(s.y, w2));
        float m = __fsub_rn(__fadd_rn(__fmul_rn(0.95f, mem), cur), rst);
        float spk = (m > 1.0f) ? 1.0f : 0.0f;
        q[(size_t)t * B_NEUR] = spk;
        mem = m;
        rst = spk;
    }
}

extern "C" void kernel_launch(void* const* d_in, const int* in_sizes, int n_in,
                              void* d_out, int out_size, void* d_ws, size_t ws_size,
                              hipStream_t stream) {
    const f4v*   sp4 = (const f4v*)d_in[0];
    const float* W   = (const float*)d_in[1];
    float*       out = (float*)d_out;

    const size_t codes_bytes = (size_t)KG * B_NEUR * 4;          // 4MB
    const size_t spec_bytes  = (size_t)NCHUNK * B_NEUR * 16;     // 1MB
    if (ws_size < codes_bytes + spec_bytes) {
        fmfm_scan_fused<<<dim3(B_NEUR / 64), dim3(64), 0, stream>>>(
            (const float2*)d_in[0], W, out);
        return;
    }
    uint32_t* codes = (uint32_t*)d_ws;
    uint4*    spec  = (uint4*)((char*)d_ws + codes_bytes);

    fmfm_compress<<<dim3(KG * (B_NEUR / 2) / 256), dim3(256), 0, stream>>>(sp4, codes);
    fmfm_scanA<<<dim3(NCHUNK * B_NEUR / 256), dim3(256), 0, stream>>>(codes, W, out, spec);
    fmfm_scanB<<<dim3(B_NEUR / 64), dim3(64), 0, stream>>>(codes, W, out, spec);
}